// Round 7
// baseline (80.048 us; speedup 1.0000x reference)
//
#include <hip/hip_runtime.h>

#define NITER 25

// fp64 rcp via v_rcp_f64 + 2 Newton refinements (~1 ulp).
__device__ __forceinline__ double fast_rcp(double x) {
#if __has_builtin(__builtin_amdgcn_rcp)
    double r = __builtin_amdgcn_rcp(x);
    r = fma(fma(-x, r, 1.0), r, r);
    r = fma(fma(-x, r, 1.0), r, r);
    return r;
#else
    return 1.0 / x;
#endif
}

// fp32 rcp for the fraction-to-boundary ratios only.
__device__ __forceinline__ float fast_rcpf(float x) {
#if __has_builtin(__builtin_amdgcn_rcpf)
    return __builtin_amdgcn_rcpf(x);
#else
    return 1.0f / x;
#endif
}

// Per-thread fp64 interior-point LCP, 25 iterations, TWO batch elements per
// thread. The solve is latency-bound (serial GE/rcp chain, only 2 chains/SIMD
// at this grid size); interleaving two independent elements per wave at
// compile time fills the fp64 latency slots. Math is operation-identical to
// the round-6 kernel (4x4 Schur system, sparse pivot network).
__global__ __launch_bounds__(256) void lcp_kernel(
    const float* __restrict__ pv, const float* __restrict__ mu_p,
    float* __restrict__ out, int half)
{
    int i = blockIdx.x * blockDim.x + threadIdx.x;
    if (i >= half) return;
    const double mu = (double)mu_p[0];
    const double SIG = 0.1;

    double q0[2], q1[2], z0[2], z1[2];
    double lam[2][4], s[2][4];

    #pragma unroll
    for (int u = 0; u < 2; ++u) {
        const float2 v = ((const float2*)pv)[i + u * half];
        q0[u] = -(double)v.x - 2.0;   // q = -v + (-2, 1), MASS=1
        q1[u] = -(double)v.y + 1.0;
        z0[u] = -q0[u]; z1[u] = -q1[u];
        #pragma unroll
        for (int k = 0; k < 4; ++k) { lam[u][k] = 1.0; s[u][k] = 1.0; }
    }

    for (int it = 0; it < NITER; ++it) {
        #pragma unroll
        for (int u = 0; u < 2; ++u) {
            // residuals (same formulas as reference)
            double rd0 = z0[u] + q0[u] + (lam[u][1] - lam[u][2]);
            double rd1 = z1[u] + q1[u] - lam[u][0];
            double rp0 = -z1[u] + s[u][0];
            double rp1 =  z0[u] + s[u][1] - lam[u][3];
            double rp2 = -z0[u] + s[u][2] - lam[u][3];
            double rp3 =  s[u][3] - (mu * lam[u][0] - lam[u][1] - lam[u][2]);

            double sl0 = s[u][0]*lam[u][0], sl1 = s[u][1]*lam[u][1];
            double sl2 = s[u][2]*lam[u][2], sl3 = s[u][3]*lam[u][3];
            double muc = 0.25 * (sl0 + sl1 + sl2 + sl3);

            double il0 = fast_rcp(lam[u][0]), il1 = fast_rcp(lam[u][1]);
            double il2 = fast_rcp(lam[u][2]), il3 = fast_rcp(lam[u][3]);
            double D0 = s[u][0]*il0, D1 = s[u][1]*il1, D2 = s[u][2]*il2, D3 = s[u][3]*il3;

            // Schur rhs: b = r_pri - r_cent/lam - G*r_dual
            double b0 = rp0 - (sl0 - SIG*muc)*il0 + rd1;
            double b1 = rp1 - (sl1 - SIG*muc)*il1 - rd0;
            double b2 = rp2 - (sl2 - SIG*muc)*il2 + rd0;
            double b3 = rp3 - (sl3 - SIG*muc)*il3;

            // ---- column 0: candidates are rows 0 and 3 only ----
            double P0[5] = { 1.0 + D0, 0.0, 0.0, 0.0, b0 };
            double P3[5] = { mu, -1.0, -1.0, D3, b3 };
            {
                bool sw = fabs(P3[0]) > fabs(P0[0]);
                #pragma unroll
                for (int c = 0; c < 5; ++c) {
                    double a = P0[c], b = P3[c];
                    P0[c] = sw ? b : a;
                    P3[c] = sw ? a : b;
                }
            }
            double ip0 = fast_rcp(P0[0]);
            {
                double f = P3[0] * ip0;
                #pragma unroll
                for (int c = 1; c < 5; ++c) P3[c] = fma(-f, P0[c], P3[c]);
            }

            // ---- pivoted 3x3 over cols 1..4 ----
            double R1[4] = { 1.0 + D1, -1.0, 1.0, b1 };
            double R2[4] = { -1.0, 1.0 + D2, 1.0, b2 };
            double R3[4] = { P3[1], P3[2], P3[3], P3[4] };

            {
                bool sw = fabs(R2[0]) > fabs(R1[0]);
                #pragma unroll
                for (int c = 0; c < 4; ++c) { double a=R1[c], b=R2[c]; R1[c]=sw?b:a; R2[c]=sw?a:b; }
            }
            {
                bool sw = fabs(R3[0]) > fabs(R1[0]);
                #pragma unroll
                for (int c = 0; c < 4; ++c) { double a=R1[c], b=R3[c]; R1[c]=sw?b:a; R3[c]=sw?a:b; }
            }
            double ip1 = fast_rcp(R1[0]);
            {
                double f2 = R2[0] * ip1;
                double f3 = R3[0] * ip1;
                #pragma unroll
                for (int c = 1; c < 4; ++c) {
                    R2[c] = fma(-f2, R1[c], R2[c]);
                    R3[c] = fma(-f3, R1[c], R3[c]);
                }
            }
            {
                bool sw = fabs(R3[1]) > fabs(R2[1]);
                #pragma unroll
                for (int c = 1; c < 4; ++c) { double a=R2[c], b=R3[c]; R2[c]=sw?b:a; R3[c]=sw?a:b; }
            }
            double ip2 = fast_rcp(R2[1]);
            {
                double f = R3[1] * ip2;
                R3[2] = fma(-f, R2[2], R3[2]);
                R3[3] = fma(-f, R2[3], R3[3]);
            }
            double ip3 = fast_rcp(R3[2]);

            // back-substitution
            double dl3 = R3[3] * ip3;
            double dl2 = (R2[3] - R2[2]*dl3) * ip2;
            double dl1 = (R1[3] - R1[1]*dl2 - R1[2]*dl3) * ip1;
            double dl0 = (P0[4] - P0[1]*dl1 - P0[2]*dl2 - P0[3]*dl3) * ip0;

            double dz0 = -rd0 - dl1 + dl2;
            double dz1 = -rd1 + dl0;

            double ds0 = -rp0 + dz1;
            double ds1 = -rp1 - dz0 + dl3;
            double ds2 = -rp2 + dz0 + dl3;
            double ds3 = -rp3 + (mu * dl0 - dl1 - dl2);

            // fraction-to-boundary: fp64 branch condition, fp32 ratio
            float amin = 3.0e12f;
            amin = fminf(amin, (dl0 < -1e-12) ? ((float)lam[u][0] * fast_rcpf((float)(-dl0))) : 3.0e12f);
            amin = fminf(amin, (dl1 < -1e-12) ? ((float)lam[u][1] * fast_rcpf((float)(-dl1))) : 3.0e12f);
            amin = fminf(amin, (dl2 < -1e-12) ? ((float)lam[u][2] * fast_rcpf((float)(-dl2))) : 3.0e12f);
            amin = fminf(amin, (dl3 < -1e-12) ? ((float)lam[u][3] * fast_rcpf((float)(-dl3))) : 3.0e12f);
            amin = fminf(amin, (ds0 < -1e-12) ? ((float)s[u][0] * fast_rcpf((float)(-ds0))) : 3.0e12f);
            amin = fminf(amin, (ds1 < -1e-12) ? ((float)s[u][1] * fast_rcpf((float)(-ds1))) : 3.0e12f);
            amin = fminf(amin, (ds2 < -1e-12) ? ((float)s[u][2] * fast_rcpf((float)(-ds2))) : 3.0e12f);
            amin = fminf(amin, (ds3 < -1e-12) ? ((float)s[u][3] * fast_rcpf((float)(-ds3))) : 3.0e12f);
            double alpha = fmin(1.0, 0.99 * (double)amin);

            z0[u] += alpha * dz0;
            z1[u] += alpha * dz1;
            lam[u][0] += alpha * dl0; lam[u][1] += alpha * dl1;
            lam[u][2] += alpha * dl2; lam[u][3] += alpha * dl3;
            s[u][0] += alpha * ds0; s[u][1] += alpha * ds1;
            s[u][2] += alpha * ds2; s[u][3] += alpha * ds3;
        }
    }

    #pragma unroll
    for (int u = 0; u < 2; ++u)
        ((float2*)out)[i + u * half] = make_float2((float)z0[u], (float)z1[u]);
}

extern "C" void kernel_launch(void* const* d_in, const int* in_sizes, int n_in,
                              void* d_out, int out_size, void* d_ws, size_t ws_size,
                              hipStream_t stream) {
    const float* pv = (const float*)d_in[0];
    const float* mu = (const float*)d_in[1];
    float* out = (float*)d_out;
    int n = in_sizes[0] / 2;  // B = 131072
    int half = n / 2;
    int block = 256;
    int grid = (half + block - 1) / block;
    lcp_kernel<<<grid, block, 0, stream>>>(pv, mu, out, half);
}